// Round 1
// baseline (376.376 us; speedup 1.0000x reference)
//
#include <hip/hip_runtime.h>
#include <math.h>

#define N_NODES_C 50000
#define N_EDGES_C 800000
#define D_FEAT_C  64

// ---------------- CSR build ----------------

__global__ void deg_kernel(const int* __restrict__ dst, int* __restrict__ deg, int nE) {
    int i = blockIdx.x * blockDim.x + threadIdx.x;
    if (i < nE) atomicAdd(&deg[dst[i]], 1);
}

// Single-block exclusive scan over n (<= ~1e5) elements; writes offs[0..n] and cursor[0..n-1].
__global__ void exscan_kernel(const int* __restrict__ deg, int* __restrict__ offs,
                              int* __restrict__ cursor, int n) {
    __shared__ int lds[16];
    __shared__ int carry_s;
    const int tid  = threadIdx.x;          // blockDim.x == 1024
    const int lane = tid & 63;
    const int wid  = tid >> 6;             // 16 waves
    if (tid == 0) carry_s = 0;
    __syncthreads();
    for (int base = 0; base < n; base += 1024) {
        int i = base + tid;
        int v = (i < n) ? deg[i] : 0;
        // inclusive scan within wave
        int x = v;
        #pragma unroll
        for (int off = 1; off < 64; off <<= 1) {
            int y = __shfl_up(x, off, 64);
            if (lane >= off) x += y;
        }
        if (lane == 63) lds[wid] = x;      // wave totals
        __syncthreads();
        if (wid == 0 && lane < 16) {
            int w = lds[lane];
            #pragma unroll
            for (int off = 1; off < 16; off <<= 1) {
                int y = __shfl_up(w, off, 16);
                if (lane >= off) w += y;
            }
            lds[lane] = w;                  // inclusive scan of wave totals
        }
        __syncthreads();
        int waveoff = (wid == 0) ? 0 : lds[wid - 1];
        int incl = x + waveoff;             // block-inclusive
        int excl = incl - v;
        int carry = carry_s;                // safe: last write was behind a barrier
        if (i < n) { offs[i] = carry + excl; cursor[i] = carry + excl; }
        __syncthreads();                    // all reads of carry_s done
        if (tid == 1023) carry_s = carry + incl;   // block total (padded lanes add 0)
        __syncthreads();
    }
    if (tid == 0) offs[n] = carry_s;
}

__global__ void fill_kernel(const int* __restrict__ src, const int* __restrict__ dst,
                            int* __restrict__ cursor, int* __restrict__ csr_src, int nE) {
    int i = blockIdx.x * blockDim.x + threadIdx.x;
    if (i < nE) {
        int pos = atomicAdd(&cursor[dst[i]], 1);
        csr_src[pos] = src[i];
    }
}

// ---------------- per-layer kernels ----------------

// Wave per node: L2-normalize one 64-float row.
__global__ void normalize_kernel(const float* __restrict__ h, float* __restrict__ nh, int n) {
    int wave = (blockIdx.x * blockDim.x + threadIdx.x) >> 6;
    int lane = threadIdx.x & 63;
    if (wave >= n) return;
    float x = h[wave * D_FEAT_C + lane];
    float ss = x * x;
    #pragma unroll
    for (int off = 32; off; off >>= 1) ss += __shfl_xor(ss, off, 64);
    float inv = 1.0f / fmaxf(sqrtf(ss), 1e-12f);
    nh[wave * D_FEAT_C + lane] = x * inv;
}

// Wave per dst node: online-softmax over incoming edges + fused weighted aggregation + relu.
__global__ void agnn_node_kernel(const float* __restrict__ h, const float* __restrict__ nh,
                                 const int* __restrict__ offs, const int* __restrict__ csr_src,
                                 const float* __restrict__ beta_ptr, int layer,
                                 float* __restrict__ out, int n) {
    int wave = (blockIdx.x * blockDim.x + threadIdx.x) >> 6;
    int lane = threadIdx.x & 63;
    if (wave >= n) return;
    int s = offs[wave], e = offs[wave + 1];
    float res = 0.f;
    if (e > s) {
        float beta = beta_ptr[layer];
        float nhd = nh[wave * D_FEAT_C + lane];
        float m = -INFINITY, den = 0.f, acc = 0.f;
        for (int j = s; j < e; ++j) {
            int u = csr_src[j];
            float d = nhd * nh[u * D_FEAT_C + lane];
            #pragma unroll
            for (int off = 32; off; off >>= 1) d += __shfl_xor(d, off, 64);
            float ev = beta * d;                 // edge score (all lanes hold it)
            float hu = h[u * D_FEAT_C + lane];
            float mn = fmaxf(m, ev);
            float sc = __expf(m - mn);           // exp(-inf)=0 on first edge
            float w  = __expf(ev - mn);
            den = den * sc + w;
            acc = acc * sc + w * hu;
            m = mn;
        }
        res = acc / den;                         // = sum h[src]*p
    }
    out[wave * D_FEAT_C + lane] = fmaxf(res, 0.f);  // relu; deg-0 nodes -> 0
}

// ---------------- launch ----------------

extern "C" void kernel_launch(void* const* d_in, const int* in_sizes, int n_in,
                              void* d_out, int out_size, void* d_ws, size_t ws_size,
                              hipStream_t stream) {
    const float* x    = (const float*)d_in[0];
    const int*   src  = (const int*)d_in[1];
    const int*   dst  = (const int*)d_in[2];
    const float* beta = (const float*)d_in[3];
    float*       out  = (float*)d_out;

    const int N = N_NODES_C, E = N_EDGES_C;

    char* p = (char*)d_ws;
    auto take = [&](size_t bytes) { char* r = p; p += (bytes + 255) & ~size_t(255); return r; };
    int*   deg     = (int*)  take(sizeof(int) * N);
    int*   offs    = (int*)  take(sizeof(int) * (N + 1));
    int*   cursor  = (int*)  take(sizeof(int) * N);
    int*   csr_src = (int*)  take(sizeof(int) * E);
    float* nh      = (float*)take(sizeof(float) * N * D_FEAT_C);
    float* h1      = (float*)take(sizeof(float) * N * D_FEAT_C);

    // CSR by dst (layer-invariant, built once per call)
    hipMemsetAsync(deg, 0, sizeof(int) * N, stream);
    deg_kernel<<<(E + 255) / 256, 256, 0, stream>>>(dst, deg, E);
    exscan_kernel<<<1, 1024, 0, stream>>>(deg, offs, cursor, N);
    fill_kernel<<<(E + 255) / 256, 256, 0, stream>>>(src, dst, cursor, csr_src, E);

    const int node_blocks = (N + 3) / 4;   // 4 waves (nodes) per 256-thread block

    // layer 0: x -> h1
    normalize_kernel<<<node_blocks, 256, 0, stream>>>(x, nh, N);
    agnn_node_kernel<<<node_blocks, 256, 0, stream>>>(x, nh, offs, csr_src, beta, 0, h1, N);

    // layer 1: h1 -> out
    normalize_kernel<<<node_blocks, 256, 0, stream>>>(h1, nh, N);
    agnn_node_kernel<<<node_blocks, 256, 0, stream>>>(h1, nh, offs, csr_src, beta, 1, out, N);
}

// Round 3
// 283.277 us; speedup vs baseline: 1.3286x; 1.3286x over previous
//
#include <hip/hip_runtime.h>
#include <math.h>

#define N_NODES_C 50000
#define N_EDGES_C 800000
#define D_FEAT_C  64

// ---------------- CSR build ----------------

__global__ void deg_kernel(const int* __restrict__ dst, int* __restrict__ deg, int nE) {
    int i = blockIdx.x * blockDim.x + threadIdx.x;
    if (i < nE) atomicAdd(&deg[dst[i]], 1);
}

// Single-block exclusive scan, 4 elements/thread (int4). n must be mult of 4 (50000 is).
__global__ void exscan_kernel(const int* __restrict__ deg, int* __restrict__ offs,
                              int* __restrict__ cursor, int n) {
    __shared__ int lds[16];
    __shared__ int carry_s;
    const int tid  = threadIdx.x;          // blockDim.x == 1024
    const int lane = tid & 63;
    const int wid  = tid >> 6;             // 16 waves
    if (tid == 0) carry_s = 0;
    __syncthreads();
    for (int base = 0; base < n; base += 4096) {
        int i = base + tid * 4;
        int4 v = make_int4(0, 0, 0, 0);
        if (i < n) v = *(const int4*)(deg + i);   // n%4==0 -> safe
        int tsum = v.x + v.y + v.z + v.w;
        // inclusive wave scan of per-thread sums
        int x = tsum;
        #pragma unroll
        for (int off = 1; off < 64; off <<= 1) {
            int y = __shfl_up(x, off, 64);
            if (lane >= off) x += y;
        }
        if (lane == 63) lds[wid] = x;
        __syncthreads();
        if (tid < 16) {
            int w = lds[tid];
            #pragma unroll
            for (int off = 1; off < 16; off <<= 1) {
                int y = __shfl_up(w, off, 16);
                if (tid >= off) w += y;
            }
            lds[tid] = w;                   // inclusive scan of wave totals
        }
        __syncthreads();
        int waveoff = wid ? lds[wid - 1] : 0;
        int excl = carry_s + waveoff + (x - tsum);  // exclusive prefix of elem 0
        if (i < n) {
            int4 o;
            o.x = excl;
            o.y = o.x + v.x;
            o.z = o.y + v.y;
            o.w = o.z + v.z;
            *(int4*)(offs + i)   = o;
            *(int4*)(cursor + i) = o;
        }
        __syncthreads();                    // all carry_s reads done
        if (tid == 1023) carry_s += lds[15];
        __syncthreads();
    }
    if (tid == 0) offs[n] = carry_s;
}

__global__ void fill_kernel(const int* __restrict__ src, const int* __restrict__ dst,
                            int* __restrict__ cursor, int* __restrict__ csr_src, int nE) {
    int i = blockIdx.x * blockDim.x + threadIdx.x;
    if (i < nE) {
        int pos = atomicAdd(&cursor[dst[i]], 1);
        csr_src[pos] = src[i];
    }
}

// ---------------- per-layer kernels ----------------

// Wave per node: compute 1/max(||row||,eps) only.
__global__ void invnorm_kernel(const float* __restrict__ h, float* __restrict__ invn, int n) {
    int wave = (blockIdx.x * blockDim.x + threadIdx.x) >> 6;
    int lane = threadIdx.x & 63;
    if (wave >= n) return;
    float x = h[wave * D_FEAT_C + lane];
    float ss = x * x;
    #pragma unroll
    for (int off = 32; off; off >>= 1) ss += __shfl_xor(ss, off, 64);
    if (lane == 0) invn[wave] = 1.0f / fmaxf(sqrtf(ss), 1e-12f);
}

// Wave per dst node (full wave per edge, R1-proven structure).
// Online softmax + fused weighted aggregation + relu. cos computed from raw
// rows scaled by the two inverse norms (no nh array). Optionally emits the
// invnorm of the relu'd output row for the next layer.
__global__ void __launch_bounds__(256)
agnn_node_kernel(const float* __restrict__ h, const float* __restrict__ invn,
                 const int* __restrict__ offs, const int* __restrict__ csr_src,
                 const float* __restrict__ beta_ptr, int layer,
                 float* __restrict__ out, float* __restrict__ invn_out, int n) {
    int wave = (blockIdx.x * blockDim.x + threadIdx.x) >> 6;
    int lane = threadIdx.x & 63;
    if (wave >= n) return;
    int s = offs[wave], e = offs[wave + 1];
    float res = 0.f;
    if (e > s) {                              // wave-uniform
        float beta = beta_ptr[layer];
        float nhd  = h[wave * D_FEAT_C + lane] * invn[wave];
        float m = -INFINITY, den = 0.f, acc = 0.f;
        for (int base = s; base < e; base += 64) {
            int idx  = base + lane;
            int eidx = (idx < e) ? csr_src[idx] : 0;   // coalesced batch of edge ids
            int nb   = min(64, e - base);               // wave-uniform
            for (int jj = 0; jj < nb; ++jj) {
                int u = __shfl(eidx, jj, 64);           // uniform srcLane
                float iu = invn[u];                     // broadcast scalar
                float hu = h[u * D_FEAT_C + lane];      // 256B row gather (reused below)
                float d  = nhd * hu;
                #pragma unroll
                for (int off = 32; off; off >>= 1) d += __shfl_xor(d, off, 64);
                float ev = beta * d * iu;               // edge score
                float mn = fmaxf(m, ev);
                float sc = __expf(m - mn);              // exp(-inf)=0 on first edge
                float w  = __expf(ev - mn);
                den = den * sc + w;
                acc = acc * sc + w * hu;
                m = mn;
            }
        }
        res = acc / den;                      // = sum h[src]*p
    }
    float ro = fmaxf(res, 0.f);               // relu; deg-0 nodes -> 0
    out[wave * D_FEAT_C + lane] = ro;
    if (invn_out) {
        float ss = ro * ro;
        #pragma unroll
        for (int off = 32; off; off >>= 1) ss += __shfl_xor(ss, off, 64);
        if (lane == 0) invn_out[wave] = 1.0f / fmaxf(sqrtf(ss), 1e-12f);
    }
}

// ---------------- launch ----------------

extern "C" void kernel_launch(void* const* d_in, const int* in_sizes, int n_in,
                              void* d_out, int out_size, void* d_ws, size_t ws_size,
                              hipStream_t stream) {
    const float* x    = (const float*)d_in[0];
    const int*   src  = (const int*)d_in[1];
    const int*   dst  = (const int*)d_in[2];
    const float* beta = (const float*)d_in[3];
    float*       out  = (float*)d_out;

    const int N = N_NODES_C, E = N_EDGES_C;

    char* p = (char*)d_ws;
    auto take = [&](size_t bytes) { char* r = p; p += (bytes + 255) & ~size_t(255); return r; };
    int*   deg     = (int*)  take(sizeof(int) * N);
    int*   offs    = (int*)  take(sizeof(int) * (N + 1));
    int*   cursor  = (int*)  take(sizeof(int) * N);
    int*   csr_src = (int*)  take(sizeof(int) * E);
    float* invnA   = (float*)take(sizeof(float) * N);
    float* invnB   = (float*)take(sizeof(float) * N);
    float* h1      = (float*)take(sizeof(float) * N * D_FEAT_C);

    // CSR by dst (layer-invariant)
    hipMemsetAsync(deg, 0, sizeof(int) * N, stream);
    deg_kernel<<<(E + 255) / 256, 256, 0, stream>>>(dst, deg, E);
    exscan_kernel<<<1, 1024, 0, stream>>>(deg, offs, cursor, N);
    fill_kernel<<<(E + 255) / 256, 256, 0, stream>>>(src, dst, cursor, csr_src, E);

    const int node_blocks = (N + 3) / 4;   // 4 waves (nodes) per 256-thread block

    // layer 0: x -> h1  (also emits invnB for layer 1)
    invnorm_kernel<<<node_blocks, 256, 0, stream>>>(x, invnA, N);
    agnn_node_kernel<<<node_blocks, 256, 0, stream>>>(x, invnA, offs, csr_src, beta, 0, h1, invnB, N);

    // layer 1: h1 -> out
    agnn_node_kernel<<<node_blocks, 256, 0, stream>>>(h1, invnB, offs, csr_src, beta, 1, out, nullptr, N);
}

// Round 4
// 262.079 us; speedup vs baseline: 1.4361x; 1.0809x over previous
//
#include <hip/hip_runtime.h>
#include <math.h>

#define N_NODES_C 50000
#define N_EDGES_C 800000
#define D_FEAT_C  64

// ---------------- CSR build ----------------

__global__ void deg_kernel(const int* __restrict__ dst, int* __restrict__ deg, int nE) {
    int i = blockIdx.x * blockDim.x + threadIdx.x;
    if (i < nE) atomicAdd(&deg[dst[i]], 1);
}

// Single-block exclusive scan, 4 elements/thread (int4). n must be mult of 4 (50000 is).
__global__ void exscan_kernel(const int* __restrict__ deg, int* __restrict__ offs,
                              int* __restrict__ cursor, int n) {
    __shared__ int lds[16];
    __shared__ int carry_s;
    const int tid  = threadIdx.x;          // blockDim.x == 1024
    const int lane = tid & 63;
    const int wid  = tid >> 6;             // 16 waves
    if (tid == 0) carry_s = 0;
    __syncthreads();
    for (int base = 0; base < n; base += 4096) {
        int i = base + tid * 4;
        int4 v = make_int4(0, 0, 0, 0);
        if (i < n) v = *(const int4*)(deg + i);   // n%4==0 -> safe
        int tsum = v.x + v.y + v.z + v.w;
        int x = tsum;
        #pragma unroll
        for (int off = 1; off < 64; off <<= 1) {
            int y = __shfl_up(x, off, 64);
            if (lane >= off) x += y;
        }
        if (lane == 63) lds[wid] = x;
        __syncthreads();
        if (tid < 16) {
            int w = lds[tid];
            #pragma unroll
            for (int off = 1; off < 16; off <<= 1) {
                int y = __shfl_up(w, off, 16);
                if (tid >= off) w += y;
            }
            lds[tid] = w;
        }
        __syncthreads();
        int waveoff = wid ? lds[wid - 1] : 0;
        int excl = carry_s + waveoff + (x - tsum);
        if (i < n) {
            int4 o;
            o.x = excl;
            o.y = o.x + v.x;
            o.z = o.y + v.y;
            o.w = o.z + v.z;
            *(int4*)(offs + i)   = o;
            *(int4*)(cursor + i) = o;
        }
        __syncthreads();
        if (tid == 1023) carry_s += lds[15];
        __syncthreads();
    }
    if (tid == 0) offs[n] = carry_s;
}

__global__ void fill_kernel(const int* __restrict__ src, const int* __restrict__ dst,
                            int* __restrict__ cursor, int* __restrict__ csr_src, int nE) {
    int i = blockIdx.x * blockDim.x + threadIdx.x;
    if (i < nE) {
        int pos = atomicAdd(&cursor[dst[i]], 1);
        csr_src[pos] = src[i];
    }
}

// ---------------- per-layer kernels ----------------

__global__ void invnorm_kernel(const float* __restrict__ h, float* __restrict__ invn, int n) {
    int wave = (blockIdx.x * blockDim.x + threadIdx.x) >> 6;
    int lane = threadIdx.x & 63;
    if (wave >= n) return;
    float x = h[wave * D_FEAT_C + lane];
    float ss = x * x;
    #pragma unroll
    for (int off = 32; off; off >>= 1) ss += __shfl_xor(ss, off, 64);
    if (lane == 0) invn[wave] = 1.0f / fmaxf(sqrtf(ss), 1e-12f);
}

// Wave per dst node. 4-edge ILP groups: 4 independent gathers + 4 interleaved
// shuffle-reduce trees + tree-max + 4 parallel exps + ONE online-softmax merge
// per group. Tail edges padded with score=-inf (weight 0) -- exact, and all
// control flow is wave-uniform.
__global__ void __launch_bounds__(256)
agnn_node_kernel(const float* __restrict__ h, const float* __restrict__ invn,
                 const int* __restrict__ offs, const int* __restrict__ csr_src,
                 const float* __restrict__ beta_ptr, int layer,
                 float* __restrict__ out, float* __restrict__ invn_out, int n) {
    int wave = (blockIdx.x * blockDim.x + threadIdx.x) >> 6;
    int lane = threadIdx.x & 63;
    if (wave >= n) return;
    int s = offs[wave], e = offs[wave + 1];
    float res = 0.f;
    if (e > s) {                              // wave-uniform
        float beta = beta_ptr[layer];
        float nhd  = h[wave * D_FEAT_C + lane] * invn[wave];
        float m = -INFINITY, den = 0.f, acc = 0.f;
        for (int base = s; base < e; base += 64) {
            int idx  = base + lane;
            int eidx = (idx < e) ? csr_src[idx] : 0;   // coalesced batch of 64 edge ids
            int nb   = min(64, e - base);               // wave-uniform
            for (int jj = 0; jj < nb; jj += 4) {
                bool v1 = jj + 1 < nb, v2 = jj + 2 < nb, v3 = jj + 3 < nb;  // uniform
                int u0 = __shfl(eidx, jj, 64);
                int u1 = __shfl(eidx, v1 ? jj + 1 : jj, 64);
                int u2 = __shfl(eidx, v2 ? jj + 2 : jj, 64);
                int u3 = __shfl(eidx, v3 ? jj + 3 : jj, 64);
                float iu0 = invn[u0], iu1 = invn[u1], iu2 = invn[u2], iu3 = invn[u3];
                float hu0 = h[u0 * D_FEAT_C + lane];
                float hu1 = h[u1 * D_FEAT_C + lane];
                float hu2 = h[u2 * D_FEAT_C + lane];
                float hu3 = h[u3 * D_FEAT_C + lane];
                float d0 = nhd * hu0, d1 = nhd * hu1, d2 = nhd * hu2, d3 = nhd * hu3;
                #pragma unroll
                for (int off = 32; off; off >>= 1) {   // 4 interleaved reduce trees
                    d0 += __shfl_xor(d0, off, 64);
                    d1 += __shfl_xor(d1, off, 64);
                    d2 += __shfl_xor(d2, off, 64);
                    d3 += __shfl_xor(d3, off, 64);
                }
                float e0 = beta * d0 * iu0;
                float e1 = v1 ? beta * d1 * iu1 : -INFINITY;
                float e2 = v2 ? beta * d2 * iu2 : -INFINITY;
                float e3 = v3 ? beta * d3 * iu3 : -INFINITY;
                float M4 = fmaxf(fmaxf(e0, e1), fmaxf(e2, e3));
                float w0 = __expf(e0 - M4), w1 = __expf(e1 - M4);
                float w2 = __expf(e2 - M4), w3 = __expf(e3 - M4);
                float den4 = (w0 + w1) + (w2 + w3);
                float acc4 = (w0 * hu0 + w1 * hu1) + (w2 * hu2 + w3 * hu3);
                // single online merge per group
                float mn = fmaxf(m, M4);
                float sc = __expf(m - mn);    // 0 on first group (m=-inf)
                float sg = __expf(M4 - mn);
                den = den * sc + den4 * sg;
                acc = acc * sc + acc4 * sg;
                m = mn;
            }
        }
        res = acc / den;                      // = sum h[src]*p
    }
    float ro = fmaxf(res, 0.f);               // relu; deg-0 nodes -> 0
    out[wave * D_FEAT_C + lane] = ro;
    if (invn_out) {
        float ss = ro * ro;
        #pragma unroll
        for (int off = 32; off; off >>= 1) ss += __shfl_xor(ss, off, 64);
        if (lane == 0) invn_out[wave] = 1.0f / fmaxf(sqrtf(ss), 1e-12f);
    }
}

// ---------------- launch ----------------

extern "C" void kernel_launch(void* const* d_in, const int* in_sizes, int n_in,
                              void* d_out, int out_size, void* d_ws, size_t ws_size,
                              hipStream_t stream) {
    const float* x    = (const float*)d_in[0];
    const int*   src  = (const int*)d_in[1];
    const int*   dst  = (const int*)d_in[2];
    const float* beta = (const float*)d_in[3];
    float*       out  = (float*)d_out;

    const int N = N_NODES_C, E = N_EDGES_C;

    char* p = (char*)d_ws;
    auto take = [&](size_t bytes) { char* r = p; p += (bytes + 255) & ~size_t(255); return r; };
    int*   deg     = (int*)  take(sizeof(int) * N);
    int*   offs    = (int*)  take(sizeof(int) * (N + 1));
    int*   cursor  = (int*)  take(sizeof(int) * N);
    int*   csr_src = (int*)  take(sizeof(int) * E);
    float* invnA   = (float*)take(sizeof(float) * N);
    float* invnB   = (float*)take(sizeof(float) * N);
    float* h1      = (float*)take(sizeof(float) * N * D_FEAT_C);

    // CSR by dst (layer-invariant)
    hipMemsetAsync(deg, 0, sizeof(int) * N, stream);
    deg_kernel<<<(E + 255) / 256, 256, 0, stream>>>(dst, deg, E);
    exscan_kernel<<<1, 1024, 0, stream>>>(deg, offs, cursor, N);
    fill_kernel<<<(E + 255) / 256, 256, 0, stream>>>(src, dst, cursor, csr_src, E);

    const int node_blocks = (N + 3) / 4;   // 4 waves (nodes) per 256-thread block

    // layer 0: x -> h1  (also emits invnB for layer 1)
    invnorm_kernel<<<node_blocks, 256, 0, stream>>>(x, invnA, N);
    agnn_node_kernel<<<node_blocks, 256, 0, stream>>>(x, invnA, offs, csr_src, beta, 0, h1, invnB, N);

    // layer 1: h1 -> out
    agnn_node_kernel<<<node_blocks, 256, 0, stream>>>(h1, invnB, offs, csr_src, beta, 1, out, nullptr, N);
}